// Round 5
// baseline (80.373 us; speedup 1.0000x reference)
//
#include <hip/hip_runtime.h>

// VocabEmbeddingWithLoRA: out[b,s,d] = W[x[b,s], d] + sum_r A[r, x[b,s]] * B[d, r]
// VOCAB=128000, D=2048, RANK=16, tokens = 4*4096 = 16384. All fp32, x int32.
//
// R5: two-kernel split.
//  Kernel A: codes[t][r] = A[r, x[t]]  -- pure 4B scatter (16.8 MB of 64B
//   lines chip-wide), fully parallel, coalesced 1 MB write into d_ws. Runs at
//   the random-scatter ceiling with nothing serialized behind it.
//  Kernel B: per block, coalesced 2 KB code load (L3-hot) + one barrier, then
//   the R4 streaming pipeline: 1024 threads = 2 dims/thread (B-fragment
//   32 VGPR), PF=4 prefetched nontemporal W-row loads, nontemporal stores.
//   No scattered reads compete with the W stream; the one __syncthreads
//   drains only a cheap L3-hot load.
// Fallback (ws too small): single-kernel R4 behavior via template<GATHER>.

#define VOCAB   128000
#define DMODEL  2048
#define RANK    16
#define TPB     32            // tokens per block (kernel B)
#define THREADS 1024          // = DMODEL/2 lanes, 2 dims per thread
#define PF      4             // prefetch depth (W row-fragments in flight)

typedef float fx4 __attribute__((ext_vector_type(4)));
typedef float fx2 __attribute__((ext_vector_type(2)));

__global__ __launch_bounds__(256)
void gather_codes_kernel(const int* __restrict__ x,
                         const float* __restrict__ A,
                         float* __restrict__ codes, int n16) {
    const int gid = blockIdx.x * 256 + threadIdx.x;
    if (gid < n16) {
        const int t = gid >> 4;
        const int r = gid & 15;
        codes[gid] = A[(size_t)r * VOCAB + (size_t)x[t]];
    }
}

template <bool GATHER>
__global__ __launch_bounds__(THREADS, 8)
void embed_lora_kernel(const int* __restrict__ x,
                       const float* __restrict__ W,
                       const float* __restrict__ A_or_codes,
                       const float* __restrict__ Bm,
                       float* __restrict__ out) {
    __shared__ fx4 code4[TPB][RANK / 4];   // per-token LoRA code, 16 floats

    const int tid   = threadIdx.x;
    const int tbase = blockIdx.x * TPB;

    if (GATHER) {
        // Fallback: scattered per-lane gather from A (R4 path).
        if (tid < TPB * RANK) {
            const int j   = tid >> 4;
            const int r   = tid & 15;
            const int tok = x[tbase + j];
            ((float*)&code4[0][0])[tid] = A_or_codes[(size_t)r * VOCAB + (size_t)tok];
        }
    } else {
        // Precomputed codes: one coalesced 2 KB block read (L3-hot).
        if (tid < TPB * RANK / 4) {   // 128 threads x 16B
            ((fx4*)&code4[0][0])[tid] =
                ((const fx4*)(A_or_codes + (size_t)tbase * RANK))[tid];
        }
    }

    // Register-resident lora_B fragment: 2 dims x 16 ranks = 32 VGPR.
    const int d0 = tid * 2;
    fx4 B0[4], B1[4];
    {
        const fx4* Bp = (const fx4*)(Bm + (size_t)d0 * RANK);
        #pragma unroll
        for (int q = 0; q < 4; ++q) {
            B0[q] = Bp[q];       // dim d0,   ranks 0..15
            B1[q] = Bp[4 + q];   // dim d0+1, ranks 0..15
        }
    }

    // W prologue BEFORE the barrier: depends only on uniform x reads.
    fx2 wbuf[PF];
    #pragma unroll
    for (int p = 0; p < PF; ++p) {
        const size_t row = (size_t)x[tbase + p] * DMODEL;   // uniform -> SGPR
        wbuf[p] = __builtin_nontemporal_load(&((const fx2*)(W + row))[tid]);
    }

    __syncthreads();

    #pragma unroll
    for (int j = 0; j < TPB; ++j) {
        const fx2 w = wbuf[j % PF];                          // static index (full unroll)
        if (j + PF < TPB) {
            const size_t row = (size_t)x[tbase + j + PF] * DMODEL;
            wbuf[j % PF] = __builtin_nontemporal_load(&((const fx2*)(W + row))[tid]);
        }

        const fx4 c0 = code4[j][0];
        const fx4 c1 = code4[j][1];
        const fx4 c2 = code4[j][2];
        const fx4 c3 = code4[j][3];

        float s0, s1;
        s0  = B0[0].x * c0.x + B0[0].y * c0.y + B0[0].z * c0.z + B0[0].w * c0.w;
        s0 += B0[1].x * c1.x + B0[1].y * c1.y + B0[1].z * c1.z + B0[1].w * c1.w;
        s0 += B0[2].x * c2.x + B0[2].y * c2.y + B0[2].z * c2.z + B0[2].w * c2.w;
        s0 += B0[3].x * c3.x + B0[3].y * c3.y + B0[3].z * c3.z + B0[3].w * c3.w;

        s1  = B1[0].x * c0.x + B1[0].y * c0.y + B1[0].z * c0.z + B1[0].w * c0.w;
        s1 += B1[1].x * c1.x + B1[1].y * c1.y + B1[1].z * c1.z + B1[1].w * c1.w;
        s1 += B1[2].x * c2.x + B1[2].y * c2.y + B1[2].z * c2.z + B1[2].w * c2.w;
        s1 += B1[3].x * c3.x + B1[3].y * c3.y + B1[3].z * c3.z + B1[3].w * c3.w;

        fx2 o;
        o.x = w.x + s0;
        o.y = w.y + s1;

        __builtin_nontemporal_store(o, &((fx2*)out)[(size_t)(tbase + j) * (DMODEL / 2) + tid]);
    }
}

extern "C" void kernel_launch(void* const* d_in, const int* in_sizes, int n_in,
                              void* d_out, int out_size, void* d_ws, size_t ws_size,
                              hipStream_t stream) {
    const int*   x  = (const int*)d_in[0];
    const float* W  = (const float*)d_in[1];
    const float* A  = (const float*)d_in[2];
    const float* Bm = (const float*)d_in[3];
    float*       o  = (float*)d_out;

    const int n_tokens = in_sizes[0];            // 16384
    const int n_blocks = n_tokens / TPB;         // 512
    const int n16      = n_tokens * RANK;        // 262144

    if (ws_size >= (size_t)n16 * sizeof(float)) {
        float* codes = (float*)d_ws;
        gather_codes_kernel<<<(n16 + 255) / 256, 256, 0, stream>>>(x, A, codes, n16);
        embed_lora_kernel<false><<<n_blocks, THREADS, 0, stream>>>(x, W, codes, Bm, o);
    } else {
        embed_lora_kernel<true><<<n_blocks, THREADS, 0, stream>>>(x, W, A, Bm, o);
    }
}

// Round 6
// 64.689 us; speedup vs baseline: 1.2424x; 1.2424x over previous
//
#include <hip/hip_runtime.h>

// VocabEmbeddingWithLoRA: out[b,s,d] = W[x[b,s], d] + sum_r A[r, x[b,s]] * B[d, r]
// VOCAB=128000, D=2048, RANK=16, tokens = 4*4096 = 16384. All fp32, x int32.
//
// R6 = R4 base (1024 thr, 2 dims/thread, 32-VGPR B-frag, PF=4 nontemporal W
// pipeline, <=64 VGPR -> 32 waves/CU) with two changes:
//  1. RAW s_barrier + lgkmcnt(0) only (no __syncthreads) -> the W prefetch
//     pipeline is NEVER vmcnt-drained; the code ds_write's gather dependency
//     resolves via a counted vmcnt wait (gather issued first = oldest).
//  2. Codes split into 2 half-tiles of 16 tokens, double-buffered in LDS:
//     half-1's scatter issues at steady-state start and hides under 16
//     W-row iterations; only half-0's scatter is exposed at t=0.

#define VOCAB   128000
#define DMODEL  2048
#define RANK    16
#define TPB     32            // tokens per block
#define HALF    16            // tokens per half-tile
#define THREADS 1024          // = DMODEL/2 lanes, 2 dims per thread
#define PF      4             // W row-fragments in flight per wave

typedef float fx4 __attribute__((ext_vector_type(4)));
typedef float fx2 __attribute__((ext_vector_type(2)));

// LDS-ordering barrier that does NOT drain vmcnt (unlike __syncthreads).
__device__ __forceinline__ void barrier_nodrain() {
    asm volatile("s_waitcnt lgkmcnt(0)" ::: "memory");
    __builtin_amdgcn_s_barrier();
    __builtin_amdgcn_sched_barrier(0);
}

__global__ __launch_bounds__(THREADS, 8)
void embed_lora_kernel(const int* __restrict__ x,
                       const float* __restrict__ W,
                       const float* __restrict__ A,
                       const float* __restrict__ Bm,
                       float* __restrict__ out) {
    __shared__ fx4 code4[2][HALF][RANK / 4];   // double-buffered token codes

    const int tid   = threadIdx.x;
    const int tbase = blockIdx.x * TPB;
    const bool gth  = (tid < HALF * RANK);     // 256 gather lanes
    const int  gj   = tid >> 4;                // token within half-tile
    const int  gr   = tid & 15;                // rank

    // Half-0 code gather -> register (issued FIRST = oldest in vmcnt queue,
    // so its consume-wait is counted, leaving W/B loads in flight).
    float c0r = 0.f;
    if (gth) c0r = A[(size_t)gr * VOCAB + (size_t)x[tbase + gj]];

    // W prologue: PF rows in flight. Uniform x -> scalar loads.
    fx2 wbuf[PF];
    #pragma unroll
    for (int p = 0; p < PF; ++p) {
        const size_t row = (size_t)x[tbase + p] * DMODEL;
        wbuf[p] = __builtin_nontemporal_load(&((const fx2*)(W + row))[tid]);
    }

    // Register-resident lora_B fragment: 2 dims x 16 ranks = 32 VGPR.
    const int d0 = tid * 2;
    fx4 B0[4], B1[4];
    {
        const fx4* Bp = (const fx4*)(Bm + (size_t)d0 * RANK);
        #pragma unroll
        for (int q = 0; q < 4; ++q) {
            B0[q] = Bp[q];       // dim d0,   ranks 0..15
            B1[q] = Bp[4 + q];   // dim d0+1, ranks 0..15
        }
    }

    // Publish half-0 codes; raw barrier keeps W/B loads outstanding.
    if (gth) ((float*)&code4[0][gj][0])[gr] = c0r;
    barrier_nodrain();

    // Issue half-1 code gather now; it hides under 16 streaming iterations.
    float c1r = 0.f;
    if (gth) c1r = A[(size_t)gr * VOCAB + (size_t)x[tbase + HALF + gj]];

    #pragma unroll
    for (int j = 0; j < HALF; ++j) {
        const fx2 w = wbuf[j % PF];
        {   // continuous W prefetch (crosses into half-1 tokens)
            const size_t row = (size_t)x[tbase + j + PF] * DMODEL;
            wbuf[j % PF] = __builtin_nontemporal_load(&((const fx2*)(W + row))[tid]);
        }
        const fx4 c0 = code4[0][j][0];
        const fx4 c1 = code4[0][j][1];
        const fx4 c2 = code4[0][j][2];
        const fx4 c3 = code4[0][j][3];

        float s0, s1;
        s0  = B0[0].x * c0.x + B0[0].y * c0.y + B0[0].z * c0.z + B0[0].w * c0.w;
        s0 += B0[1].x * c1.x + B0[1].y * c1.y + B0[1].z * c1.z + B0[1].w * c1.w;
        s0 += B0[2].x * c2.x + B0[2].y * c2.y + B0[2].z * c2.z + B0[2].w * c2.w;
        s0 += B0[3].x * c3.x + B0[3].y * c3.y + B0[3].z * c3.z + B0[3].w * c3.w;
        s1  = B1[0].x * c0.x + B1[0].y * c0.y + B1[0].z * c0.z + B1[0].w * c0.w;
        s1 += B1[1].x * c1.x + B1[1].y * c1.y + B1[1].z * c1.z + B1[1].w * c1.w;
        s1 += B1[2].x * c2.x + B1[2].y * c2.y + B1[2].z * c2.z + B1[2].w * c2.w;
        s1 += B1[3].x * c3.x + B1[3].y * c3.y + B1[3].z * c3.z + B1[3].w * c3.w;

        fx2 o; o.x = w.x + s0; o.y = w.y + s1;
        __builtin_nontemporal_store(o, &((fx2*)out)[(size_t)(tbase + j) * (DMODEL / 2) + tid]);
    }

    // Publish half-1 codes (its gather finished long ago); no vmcnt drain.
    if (gth) ((float*)&code4[1][gj][0])[gr] = c1r;
    barrier_nodrain();

    #pragma unroll
    for (int j = HALF; j < TPB; ++j) {
        const fx2 w = wbuf[j % PF];
        if (j + PF < TPB) {
            const size_t row = (size_t)x[tbase + j + PF] * DMODEL;
            wbuf[j % PF] = __builtin_nontemporal_load(&((const fx2*)(W + row))[tid]);
        }
        const fx4 c0 = code4[1][j - HALF][0];
        const fx4 c1 = code4[1][j - HALF][1];
        const fx4 c2 = code4[1][j - HALF][2];
        const fx4 c3 = code4[1][j - HALF][3];

        float s0, s1;
        s0  = B0[0].x * c0.x + B0[0].y * c0.y + B0[0].z * c0.z + B0[0].w * c0.w;
        s0 += B0[1].x * c1.x + B0[1].y * c1.y + B0[1].z * c1.z + B0[1].w * c1.w;
        s0 += B0[2].x * c2.x + B0[2].y * c2.y + B0[2].z * c2.z + B0[2].w * c2.w;
        s0 += B0[3].x * c3.x + B0[3].y * c3.y + B0[3].z * c3.z + B0[3].w * c3.w;
        s1  = B1[0].x * c0.x + B1[0].y * c0.y + B1[0].z * c0.z + B1[0].w * c0.w;
        s1 += B1[1].x * c1.x + B1[1].y * c1.y + B1[1].z * c1.z + B1[1].w * c1.w;
        s1 += B1[2].x * c2.x + B1[2].y * c2.y + B1[2].z * c2.z + B1[2].w * c2.w;
        s1 += B1[3].x * c3.x + B1[3].y * c3.y + B1[3].z * c3.z + B1[3].w * c3.w;

        fx2 o; o.x = w.x + s0; o.y = w.y + s1;
        __builtin_nontemporal_store(o, &((fx2*)out)[(size_t)(tbase + j) * (DMODEL / 2) + tid]);
    }
}

extern "C" void kernel_launch(void* const* d_in, const int* in_sizes, int n_in,
                              void* d_out, int out_size, void* d_ws, size_t ws_size,
                              hipStream_t stream) {
    const int*   x  = (const int*)d_in[0];
    const float* W  = (const float*)d_in[1];
    const float* A  = (const float*)d_in[2];
    const float* Bm = (const float*)d_in[3];
    float*       o  = (float*)d_out;

    const int n_tokens = in_sizes[0];            // 16384
    const int n_blocks = n_tokens / TPB;         // 512

    embed_lora_kernel<<<n_blocks, THREADS, 0, stream>>>(x, W, A, Bm, o);
}

// Round 7
// 64.245 us; speedup vs baseline: 1.2510x; 1.0069x over previous
//
#include <hip/hip_runtime.h>

// VocabEmbeddingWithLoRA: out[b,s,d] = W[x[b,s], d] + sum_r A[r, x[b,s]] * B[d, r]
// VOCAB=128000, D=2048, RANK=16, tokens = 4*4096 = 16384. All fp32, x int32.
//
// R7 = R4 (best, 62.1 us) with EXACTLY ONE change: the __syncthreads() is
// replaced by lgkmcnt(0)+s_barrier (no vmcnt drain), so the PF=4 W prefetch
// pipeline and B-fragment loads stay in flight across the barrier. Everything
// else identical: 1024 thr, 2 dims/thread (B-frag 32 VGPR, <=64 total ->
// 8 waves/SIMD), single LDS code tile, nontemporal W loads + stores.

#define VOCAB   128000
#define DMODEL  2048
#define RANK    16
#define TPB     32            // tokens per block
#define THREADS 1024          // = DMODEL/2 lanes, 2 dims per thread
#define PF      4             // prefetch depth (W row-fragments in flight)

typedef float fx4 __attribute__((ext_vector_type(4)));
typedef float fx2 __attribute__((ext_vector_type(2)));

// LDS-ordering barrier that does NOT drain vmcnt (unlike __syncthreads).
__device__ __forceinline__ void barrier_nodrain() {
    asm volatile("s_waitcnt lgkmcnt(0)" ::: "memory");
    __builtin_amdgcn_s_barrier();
    __builtin_amdgcn_sched_barrier(0);
}

__global__ __launch_bounds__(THREADS, 8)
void embed_lora_kernel(const int* __restrict__ x,
                       const float* __restrict__ W,
                       const float* __restrict__ A,
                       const float* __restrict__ Bm,
                       float* __restrict__ out) {
    __shared__ fx4 code4[TPB][RANK / 4];   // per-token LoRA code, 16 floats

    const int tid   = threadIdx.x;
    const int tbase = blockIdx.x * TPB;

    // Gather per-token codes: 512 of 1024 threads = 32 tokens x 16 ranks.
    // Issued FIRST -> oldest in the vmcnt queue, so the ds_write's wait is
    // counted and leaves the W/B loads below still outstanding.
    if (tid < 512) {
        const int j   = tid >> 4;
        const int r   = tid & 15;
        const int tok = x[tbase + j];
        ((float*)&code4[0][0])[tid] = A[(size_t)r * VOCAB + (size_t)tok];
    }

    // Register-resident lora_B fragment: 2 dims x 16 ranks = 32 VGPR.
    const int d0 = tid * 2;
    fx4 B0[4], B1[4];
    {
        const fx4* Bp = (const fx4*)(Bm + (size_t)d0 * RANK);
        #pragma unroll
        for (int q = 0; q < 4; ++q) {
            B0[q] = Bp[q];       // dim d0,   ranks 0..15
            B1[q] = Bp[4 + q];   // dim d0+1, ranks 0..15
        }
    }

    // W prologue: depends only on uniform x reads -> scalar path.
    fx2 wbuf[PF];
    #pragma unroll
    for (int p = 0; p < PF; ++p) {
        const size_t row = (size_t)x[tbase + p] * DMODEL;   // uniform -> SGPR
        wbuf[p] = __builtin_nontemporal_load(&((const fx2*)(W + row))[tid]);
    }

    barrier_nodrain();   // LDS codes visible; W/B loads stay in flight.

    #pragma unroll
    for (int j = 0; j < TPB; ++j) {
        const fx2 w = wbuf[j % PF];                          // static index (full unroll)
        if (j + PF < TPB) {
            const size_t row = (size_t)x[tbase + j + PF] * DMODEL;
            wbuf[j % PF] = __builtin_nontemporal_load(&((const fx2*)(W + row))[tid]);
        }

        const fx4 c0 = code4[j][0];
        const fx4 c1 = code4[j][1];
        const fx4 c2 = code4[j][2];
        const fx4 c3 = code4[j][3];

        float s0, s1;
        s0  = B0[0].x * c0.x + B0[0].y * c0.y + B0[0].z * c0.z + B0[0].w * c0.w;
        s0 += B0[1].x * c1.x + B0[1].y * c1.y + B0[1].z * c1.z + B0[1].w * c1.w;
        s0 += B0[2].x * c2.x + B0[2].y * c2.y + B0[2].z * c2.z + B0[2].w * c2.w;
        s0 += B0[3].x * c3.x + B0[3].y * c3.y + B0[3].z * c3.z + B0[3].w * c3.w;

        s1  = B1[0].x * c0.x + B1[0].y * c0.y + B1[0].z * c0.z + B1[0].w * c0.w;
        s1 += B1[1].x * c1.x + B1[1].y * c1.y + B1[1].z * c1.z + B1[1].w * c1.w;
        s1 += B1[2].x * c2.x + B1[2].y * c2.y + B1[2].z * c2.z + B1[2].w * c2.w;
        s1 += B1[3].x * c3.x + B1[3].y * c3.y + B1[3].z * c3.z + B1[3].w * c3.w;

        fx2 o;
        o.x = w.x + s0;
        o.y = w.y + s1;

        __builtin_nontemporal_store(o, &((fx2*)out)[(size_t)(tbase + j) * (DMODEL / 2) + tid]);
    }
}

extern "C" void kernel_launch(void* const* d_in, const int* in_sizes, int n_in,
                              void* d_out, int out_size, void* d_ws, size_t ws_size,
                              hipStream_t stream) {
    const int*   x  = (const int*)d_in[0];
    const float* W  = (const float*)d_in[1];
    const float* A  = (const float*)d_in[2];
    const float* Bm = (const float*)d_in[3];
    float*       o  = (float*)d_out;

    const int n_tokens = in_sizes[0];            // 16384
    const int n_blocks = n_tokens / TPB;         // 512

    embed_lora_kernel<<<n_blocks, THREADS, 0, stream>>>(x, W, A, Bm, o);
}

// Round 8
// 62.591 us; speedup vs baseline: 1.2841x; 1.0264x over previous
//
#include <hip/hip_runtime.h>

// VocabEmbeddingWithLoRA: out[b,s,d] = W[x[b,s], d] + sum_r A[r, x[b,s]] * B[d, r]
// VOCAB=128000, D=2048, RANK=16, tokens = 4*4096 = 16384. All fp32, x int32.
//
// FINAL (= R4, best measured 62.1 us ~ 4.5 TB/s effective on 277 MB traffic):
//  - 1024 threads/block = 2 output dims/thread; lora_B fragment 2x16 = 32 VGPR
//    in registers; total <=64 VGPR -> 8 waves/SIMD (hardware-max occupancy).
//  - 32 tokens/block, grid 512 (all co-resident).
//  - Per-token LoRA codes gathered once into LDS (scattered 4B reads, 512
//    lanes), consumed as uniform-address broadcasts (conflict-free).
//  - W rows: scalar-path token ids (uniform -> s_load + saddr) with PF=4
//    explicit software pipeline of nontemporal 8B loads; nontemporal stores.
// Verdict: DRAM-efficiency roofline for a random-8KB-row gather (134 MB) +
// 64B-line scatter (16 MB) + streaming write (134 MB); all structural
// variants (occupancy x2, kernel split, no-drain barrier, half-tile dbuf)
// land within 62-65 us.

#define VOCAB   128000
#define DMODEL  2048
#define RANK    16
#define TPB     32            // tokens per block
#define THREADS 1024          // = DMODEL/2 lanes, 2 dims per thread
#define PF      4             // prefetch depth (W row-fragments in flight)

typedef float fx4 __attribute__((ext_vector_type(4)));
typedef float fx2 __attribute__((ext_vector_type(2)));

__global__ __launch_bounds__(THREADS, 8)
void embed_lora_kernel(const int* __restrict__ x,
                       const float* __restrict__ W,
                       const float* __restrict__ A,
                       const float* __restrict__ Bm,
                       float* __restrict__ out) {
    __shared__ fx4 code4[TPB][RANK / 4];   // per-token LoRA code, 16 floats

    const int tid   = threadIdx.x;
    const int tbase = blockIdx.x * TPB;

    // Gather per-token codes: 512 of 1024 threads = 32 tokens x 16 ranks.
    if (tid < 512) {
        const int j   = tid >> 4;
        const int r   = tid & 15;
        const int tok = x[tbase + j];
        ((float*)&code4[0][0])[tid] = A[(size_t)r * VOCAB + (size_t)tok];
    }

    // Register-resident lora_B fragment: 2 dims x 16 ranks = 32 VGPR.
    const int d0 = tid * 2;
    fx4 B0[4], B1[4];
    {
        const fx4* Bp = (const fx4*)(Bm + (size_t)d0 * RANK);
        #pragma unroll
        for (int q = 0; q < 4; ++q) {
            B0[q] = Bp[q];       // dim d0,   ranks 0..15
            B1[q] = Bp[4 + q];   // dim d0+1, ranks 0..15
        }
    }

    // W prologue BEFORE the barrier: depends only on uniform x reads.
    fx2 wbuf[PF];
    #pragma unroll
    for (int p = 0; p < PF; ++p) {
        const size_t row = (size_t)x[tbase + p] * DMODEL;   // uniform -> SGPR
        wbuf[p] = __builtin_nontemporal_load(&((const fx2*)(W + row))[tid]);
    }

    __syncthreads();

    #pragma unroll
    for (int j = 0; j < TPB; ++j) {
        const fx2 w = wbuf[j % PF];                          // static index (full unroll)
        if (j + PF < TPB) {
            const size_t row = (size_t)x[tbase + j + PF] * DMODEL;
            wbuf[j % PF] = __builtin_nontemporal_load(&((const fx2*)(W + row))[tid]);
        }

        const fx4 c0 = code4[j][0];
        const fx4 c1 = code4[j][1];
        const fx4 c2 = code4[j][2];
        const fx4 c3 = code4[j][3];

        float s0, s1;
        s0  = B0[0].x * c0.x + B0[0].y * c0.y + B0[0].z * c0.z + B0[0].w * c0.w;
        s0 += B0[1].x * c1.x + B0[1].y * c1.y + B0[1].z * c1.z + B0[1].w * c1.w;
        s0 += B0[2].x * c2.x + B0[2].y * c2.y + B0[2].z * c2.z + B0[2].w * c2.w;
        s0 += B0[3].x * c3.x + B0[3].y * c3.y + B0[3].z * c3.z + B0[3].w * c3.w;

        s1  = B1[0].x * c0.x + B1[0].y * c0.y + B1[0].z * c0.z + B1[0].w * c0.w;
        s1 += B1[1].x * c1.x + B1[1].y * c1.y + B1[1].z * c1.z + B1[1].w * c1.w;
        s1 += B1[2].x * c2.x + B1[2].y * c2.y + B1[2].z * c2.z + B1[2].w * c2.w;
        s1 += B1[3].x * c3.x + B1[3].y * c3.y + B1[3].z * c3.z + B1[3].w * c3.w;

        fx2 o;
        o.x = w.x + s0;
        o.y = w.y + s1;

        __builtin_nontemporal_store(o, &((fx2*)out)[(size_t)(tbase + j) * (DMODEL / 2) + tid]);
    }
}

extern "C" void kernel_launch(void* const* d_in, const int* in_sizes, int n_in,
                              void* d_out, int out_size, void* d_ws, size_t ws_size,
                              hipStream_t stream) {
    const int*   x  = (const int*)d_in[0];
    const float* W  = (const float*)d_in[1];
    const float* A  = (const float*)d_in[2];
    const float* Bm = (const float*)d_in[3];
    float*       o  = (float*)d_out;

    const int n_tokens = in_sizes[0];            // 16384
    const int n_blocks = n_tokens / TPB;         // 512

    embed_lora_kernel<<<n_blocks, THREADS, 0, stream>>>(x, W, A, Bm, o);
}